// Round 3
// baseline (234.013 us; speedup 1.0000x reference)
//
#include <hip/hip_runtime.h>
#include <hip/hip_bf16.h>

typedef __attribute__((ext_vector_type(8))) short short8;
typedef __attribute__((ext_vector_type(4))) float f32x4;

#define B_   16
#define O_   512
#define C_   512
#define T_   4096
#define TP   (T_ + 32)     // padded t extent: 16 zero rows each side
#define KT   5
#define BM   128
#define BN   256
#define BK   32
#define NCHUNK (C_/BK)

__device__ __forceinline__ void gload_lds16(const void* g, void* l) {
    __builtin_amdgcn_global_load_lds(
        (const __attribute__((address_space(1))) unsigned int*)g,
        (__attribute__((address_space(3))) unsigned int*)l, 16, 0, 0);
}

// ---------------- weight repack: w[o][c][n] f32 -> Wb[n][o][c] bf16 ----------------
__global__ void wrepack_kernel(const float* __restrict__ w, unsigned short* __restrict__ wb) {
    int e = blockIdx.x * 256 + threadIdx.x;
    if (e >= KT * O_ * C_) return;
    int n   = e / (O_ * C_);
    int rem = e % (O_ * C_);
    int o   = rem / C_;
    int c   = rem % C_;
    float v = w[((size_t)o * C_ + c) * KT + n];
    __hip_bfloat16 h = __float2bfloat16(v);
    wb[e] = *reinterpret_cast<unsigned short*>(&h);
}

// ---------------- zero the pad rows of xT ----------------
__global__ void padzero_kernel(unsigned short* __restrict__ xt) {
    int i = blockIdx.x * 256 + threadIdx.x;
    if (i >= B_ * 32 * C_) return;
    int b = i / (32 * C_);
    int r = (i / C_) % 32;
    int c = i % C_;
    int tp = (r < 16) ? r : (T_ + r);   // [0,16) and [T_+16, T_+32)
    xt[((size_t)b * TP + tp) * C_ + c] = 0;
}

// ---------------- x transpose: x[b][c][t] f32 -> xT[b][16+t][c] bf16 ----------------
__global__ void xtrans_kernel(const float* __restrict__ x, unsigned short* __restrict__ xt) {
    __shared__ float tile[64][65];
    int b  = blockIdx.z;
    int c0 = blockIdx.y * 64;
    int t0 = blockIdx.x * 64;
    const float* xb = x + ((size_t)b * C_ + c0) * T_ + t0;
#pragma unroll
    for (int p = 0; p < 4; ++p) {
        int idx = p * 256 + threadIdx.x;
        int cl = idx >> 4;
        int tj = (idx & 15) << 2;
        float4 v = *reinterpret_cast<const float4*>(xb + (size_t)cl * T_ + tj);
        tile[cl][tj + 0] = v.x;
        tile[cl][tj + 1] = v.y;
        tile[cl][tj + 2] = v.z;
        tile[cl][tj + 3] = v.w;
    }
    __syncthreads();
    unsigned short* xtb = xt + ((size_t)b * TP + 16 + t0) * C_ + c0;
#pragma unroll
    for (int p = 0; p < 2; ++p) {
        int g  = p * 256 + threadIdx.x;
        int tl = g >> 3;
        int cj = (g & 7) << 3;
        unsigned short tmp[8];
#pragma unroll
        for (int i = 0; i < 8; ++i) {
            __hip_bfloat16 h = __float2bfloat16(tile[cj + i][tl]);
            tmp[i] = *reinterpret_cast<unsigned short*>(&h);
        }
        *reinterpret_cast<short8*>(xtb + (size_t)tl * C_ + cj) =
            *reinterpret_cast<const short8*>(tmp);
    }
}

// ---------------- conv-as-GEMM, double-buffered issue-early pipeline ----------------
// Tile 128(o) x 256(t), BK=32, 8 waves (2M x 4N), wave tile 64x64.
// A: fragment-major LDS (zero-conflict). B: row-major [272][32], XOR slot swizzle.
__global__ __launch_bounds__(512, 1) void conv_gemm_kernel(
        const unsigned short* __restrict__ wb,
        const unsigned short* __restrict__ xt,
        const float* __restrict__ bias,
        float* __restrict__ out) {
    __shared__ unsigned short a_lds[2][KT * 8 * 512];   // 2 x 40960 B
    __shared__ unsigned short b_lds[2][272 * 32];       // 2 x 17408 B

    // XCD-aware bijective swizzle: 1024 blocks, o-tile innermost so the 4
    // blocks sharing a B-panel are consecutive -> same XCD L2.
    int bid = blockIdx.x;
    int swz = (bid & 7) * 128 + (bid >> 3);
    int o_t = swz & 3;
    int t_t = (swz >> 2) & 15;
    int b   = swz >> 6;
    int o0  = o_t * BM;
    int t0  = t_t * BN;

    int tid  = threadIdx.x;
    int lane = tid & 63;
    int wid  = tid >> 6;       // 0..7
    int wm   = wid >> 2;       // 0..1
    int wn   = wid & 3;        // 0..3
    int lr   = lane & 15;
    int lg   = lane >> 4;

    // chunk-invariant B read offsets (ushort units)
    int bo[KT][4];
#pragma unroll
    for (int n = 0; n < KT; ++n)
#pragma unroll
        for (int ni = 0; ni < 4; ++ni) {
            int row = wn * 64 + ni * 16 + lr + 4 - n;
            bo[n][ni] = row * 32 + ((lg ^ ((row >> 1) & 3)) << 3);
        }

    f32x4 acc[4][4];
#pragma unroll
    for (int mi = 0; mi < 4; ++mi)
#pragma unroll
        for (int ni = 0; ni < 4; ++ni)
            acc[mi][ni] = (f32x4)0.0f;

    // per-lane global staging bases
    const unsigned short* ag = wb + (size_t)(o0 + lr) * C_ + lg * 8;
    int c8 = (lane & 3) ^ ((lane >> 3) & 3);
    const unsigned short* bg = xt + ((size_t)b * TP + (t0 + 14 + (lane >> 2))) * C_ + c8 * 8;

    // ---- prologue: stage chunk 0 into buffer 0
#pragma unroll
    for (int f = wid; f < 40; f += 8)
        gload_lds16(ag + (size_t)((f >> 3) * O_ + (f & 7) * 16) * C_, &a_lds[0][f * 512]);
#pragma unroll
    for (int j = wid; j < 17; j += 8)
        gload_lds16(bg + (size_t)(j * 16) * C_, &b_lds[0][j * 512]);
    __syncthreads();

    for (int chunk = 0; chunk < NCHUNK; ++chunk) {
        int cur = chunk & 1;

        // ---- issue next chunk's staging EARLY (lands during this chunk's MFMAs)
        if (chunk + 1 < NCHUNK) {
            int c0 = (chunk + 1) * BK;
#pragma unroll
            for (int f = wid; f < 40; f += 8)
                gload_lds16(ag + (size_t)((f >> 3) * O_ + (f & 7) * 16) * C_ + c0,
                            &a_lds[cur ^ 1][f * 512]);
#pragma unroll
            for (int j = wid; j < 17; j += 8)
                gload_lds16(bg + (size_t)(j * 16) * C_ + c0, &b_lds[cur ^ 1][j * 512]);
        }

        // ---- compute this chunk: 5 taps x 16 MFMA
#pragma unroll
        for (int n = 0; n < KT; ++n) {
            short8 af[4], bf[4];
#pragma unroll
            for (int mi = 0; mi < 4; ++mi)
                af[mi] = *reinterpret_cast<const short8*>(
                    &a_lds[cur][(n * 8 + wm * 4 + mi) * 512 + lane * 8]);
#pragma unroll
            for (int ni = 0; ni < 4; ++ni)
                bf[ni] = *reinterpret_cast<const short8*>(&b_lds[cur][bo[n][ni]]);
            __builtin_amdgcn_s_setprio(1);
#pragma unroll
            for (int mi = 0; mi < 4; ++mi)
#pragma unroll
                for (int ni = 0; ni < 4; ++ni)
                    acc[mi][ni] = __builtin_amdgcn_mfma_f32_16x16x32_bf16(
                        af[mi], bf[ni], acc[mi][ni], 0, 0, 0);
            __builtin_amdgcn_s_setprio(0);
        }
        __syncthreads();   // drains vmcnt (next buf staged) + separates buffers
    }

    // ---- epilogue: C/D layout col=lane&15, row=(lane>>4)*4+reg
#pragma unroll
    for (int mi = 0; mi < 4; ++mi) {
#pragma unroll
        for (int ni = 0; ni < 4; ++ni) {
            int orow = o0 + wm * 64 + mi * 16 + lg * 4;
            int tcol = t0 + wn * 64 + ni * 16 + lr;
#pragma unroll
            for (int r = 0; r < 4; ++r) {
                out[((size_t)b * O_ + orow + r) * T_ + tcol] =
                    acc[mi][ni][r] + bias[orow + r];
            }
        }
    }
}

extern "C" void kernel_launch(void* const* d_in, const int* in_sizes, int n_in,
                              void* d_out, int out_size, void* d_ws, size_t ws_size,
                              hipStream_t stream) {
    const float* x    = (const float*)d_in[0];
    const float* w    = (const float*)d_in[1];
    const float* bias = (const float*)d_in[2];
    float* out        = (float*)d_out;

    unsigned short* wb  = (unsigned short*)d_ws;            // 2.62 MB
    unsigned short* xtp = wb + (size_t)KT * O_ * C_;        // 16*4128*512 bf16 = 67.7 MB

    padzero_kernel<<<(B_ * 32 * C_ + 255) / 256, 256, 0, stream>>>(xtp);
    wrepack_kernel<<<(KT * O_ * C_ + 255) / 256, 256, 0, stream>>>(w, wb);
    xtrans_kernel<<<dim3(T_ / 64, C_ / 64, B_), 256, 0, stream>>>(x, xtp);
    conv_gemm_kernel<<<1024, 512, 0, stream>>>(wb, xtp, bias, out);
}

// Round 4
// 193.573 us; speedup vs baseline: 1.2089x; 1.2089x over previous
//
#include <hip/hip_runtime.h>
#include <hip/hip_bf16.h>

typedef __attribute__((ext_vector_type(8))) short short8;
typedef __attribute__((ext_vector_type(4))) float f32x4;

#define B_   16
#define O_   512
#define C_   512
#define T_   4096
#define TP   (T_ + 32)     // padded t extent: 16 zero rows each side
#define KT   5
#define BM   128
#define BN   512
#define BK   32
#define NCHUNK (C_/BK)
#define AFR  40            // A fragments: 5 taps x 8 rowblocks, 1024B each
#define BGR  33            // B row-groups: 33 x 16 rows x 64B

__device__ __forceinline__ void gload_lds16(const void* g, void* l) {
    __builtin_amdgcn_global_load_lds(
        (const __attribute__((address_space(1))) unsigned int*)g,
        (__attribute__((address_space(3))) unsigned int*)l, 16, 0, 0);
}

// ---------------- weight repack: w[o][c][n] f32 -> Wb[n][o][c] bf16 ----------------
__global__ void wrepack_kernel(const float* __restrict__ w, unsigned short* __restrict__ wb) {
    int e = blockIdx.x * 256 + threadIdx.x;
    if (e >= KT * O_ * C_) return;
    int n   = e / (O_ * C_);
    int rem = e % (O_ * C_);
    int o   = rem / C_;
    int c   = rem % C_;
    float v = w[((size_t)o * C_ + c) * KT + n];
    __hip_bfloat16 h = __float2bfloat16(v);
    wb[e] = *reinterpret_cast<unsigned short*>(&h);
}

// ---------------- zero the pad rows of xT ----------------
__global__ void padzero_kernel(unsigned short* __restrict__ xt) {
    int i = blockIdx.x * 256 + threadIdx.x;
    if (i >= B_ * 32 * C_) return;
    int b = i / (32 * C_);
    int r = (i / C_) % 32;
    int c = i % C_;
    int tp = (r < 16) ? r : (T_ + r);   // [0,16) and [T_+16, T_+32)
    xt[((size_t)b * TP + tp) * C_ + c] = 0;
}

// ---------------- x transpose: x[b][c][t] f32 -> xT[b][16+t][c] bf16 ----------------
__global__ void xtrans_kernel(const float* __restrict__ x, unsigned short* __restrict__ xt) {
    __shared__ float tile[64][65];
    int b  = blockIdx.z;
    int c0 = blockIdx.y * 64;
    int t0 = blockIdx.x * 64;
    const float* xb = x + ((size_t)b * C_ + c0) * T_ + t0;
#pragma unroll
    for (int p = 0; p < 4; ++p) {
        int idx = p * 256 + threadIdx.x;
        int cl = idx >> 4;
        int tj = (idx & 15) << 2;
        float4 v = *reinterpret_cast<const float4*>(xb + (size_t)cl * T_ + tj);
        tile[cl][tj + 0] = v.x;
        tile[cl][tj + 1] = v.y;
        tile[cl][tj + 2] = v.z;
        tile[cl][tj + 3] = v.w;
    }
    __syncthreads();
    unsigned short* xtb = xt + ((size_t)b * TP + 16 + t0) * C_ + c0;
#pragma unroll
    for (int p = 0; p < 2; ++p) {
        int g  = p * 256 + threadIdx.x;
        int tl = g >> 3;
        int cj = (g & 7) << 3;
        unsigned short tmp[8];
#pragma unroll
        for (int i = 0; i < 8; ++i) {
            __hip_bfloat16 h = __float2bfloat16(tile[cj + i][tl]);
            tmp[i] = *reinterpret_cast<unsigned short*>(&h);
        }
        *reinterpret_cast<short8*>(xtb + (size_t)tl * C_ + cj) =
            *reinterpret_cast<const short8*>(tmp);
    }
}

// ---------------- conv-as-GEMM, phased (T3) pipeline ----------------
// Block tile 128(o) x 512(t), BK=32, 8 waves, wave tile 128x64 (1M x 8N).
// A: fragment-major LDS (zero-conflict). B: row-major [528][32], XOR slot swizzle.
// Per chunk: 5 phases (one per tap): {12 ds_read; 1-2 gload_lds prefetch;
// barrier; lgkmcnt(0)+sched_barrier; 32 MFMA}. vmcnt drained once per chunk.
__global__ __launch_bounds__(512, 2) void conv_gemm_kernel(
        const unsigned short* __restrict__ wb,
        const unsigned short* __restrict__ xt,
        const float* __restrict__ bias,
        float* __restrict__ out) {
    __shared__ unsigned short a_lds[2][AFR * 512];   // 2 x 40960 B
    __shared__ unsigned short b_lds[2][BGR * 512];   // 2 x 33792 B

    // XCD-aware bijective swizzle (512 blocks, 512%8==0): o-tile innermost so
    // the 4 blocks sharing a B-panel are consecutive on one XCD.
    int bid = blockIdx.x;
    int swz = (bid & 7) * 64 + (bid >> 3);
    int o0  = (swz & 3) * BM;
    int t0  = ((swz >> 2) & 7) * BN;
    int b   = swz >> 5;

    int tid  = threadIdx.x;
    int lane = tid & 63;
    int wid  = tid >> 6;       // 0..7 = wave n-position
    int lr   = lane & 15;
    int lg   = lane >> 4;

    // chunk-invariant B read offsets (ushort units)
    int bo[KT][4];
#pragma unroll
    for (int n = 0; n < KT; ++n)
#pragma unroll
        for (int ni = 0; ni < 4; ++ni) {
            int row = wid * 64 + ni * 16 + lr + 4 - n;
            bo[n][ni] = row * 32 + ((lg ^ ((row >> 1) & 3)) << 3);
        }

    f32x4 acc[8][4];
#pragma unroll
    for (int mi = 0; mi < 8; ++mi)
#pragma unroll
        for (int ni = 0; ni < 4; ++ni)
            acc[mi][ni] = (f32x4)0.0f;

    // per-lane global staging bases
    const unsigned short* ag = wb + (size_t)(o0 + lr) * C_ + lg * 8;
    int c8 = (lane & 3) ^ ((lane >> 3) & 3);
    const unsigned short* bg = xt + ((size_t)b * TP + (t0 + 14 + (lane >> 2))) * C_ + c8 * 8;

    // ---- prologue: stage chunk 0 into buffer 0
#pragma unroll
    for (int f = wid; f < AFR; f += 8)
        gload_lds16(ag + (size_t)((f >> 3) * O_ + (f & 7) * 16) * C_, &a_lds[0][f * 512]);
#pragma unroll
    for (int j = wid; j < BGR; j += 8)
        gload_lds16(bg + (size_t)(j * 16) * C_, &b_lds[0][j * 512]);
    asm volatile("s_waitcnt vmcnt(0)" ::: "memory");
    __builtin_amdgcn_s_barrier();

    for (int chunk = 0; chunk < NCHUNK; ++chunk) {
        int cur = chunk & 1;
        int c1  = (chunk + 1) * BK;
        bool pf = (chunk + 1 < NCHUNK);

#pragma unroll
        for (int n = 0; n < KT; ++n) {
            // ---- phase n: read tap n's fragments
            short8 af[8], bf[4];
#pragma unroll
            for (int mi = 0; mi < 8; ++mi)
                af[mi] = *reinterpret_cast<const short8*>(
                    &a_lds[cur][(n * 8 + mi) * 512 + lane * 8]);
#pragma unroll
            for (int ni = 0; ni < 4; ++ni)
                bf[ni] = *reinterpret_cast<const short8*>(&b_lds[cur][bo[n][ni]]);

            // ---- prefetch slice for chunk+1 (1 A group + <=1 B group per wave)
            if (pf) {
                int f = n * 8 + wid;
                gload_lds16(ag + (size_t)((f >> 3) * O_ + (f & 7) * 16) * C_ + c1,
                            &a_lds[cur ^ 1][f * 512]);
                int j = n * 8 + wid;
                if (j < BGR)
                    gload_lds16(bg + (size_t)(j * 16) * C_ + c1, &b_lds[cur ^ 1][j * 512]);
            }

            __builtin_amdgcn_s_barrier();
            asm volatile("s_waitcnt lgkmcnt(0)" ::: "memory");
            __builtin_amdgcn_sched_barrier(0);

            __builtin_amdgcn_s_setprio(1);
#pragma unroll
            for (int mi = 0; mi < 8; ++mi)
#pragma unroll
                for (int ni = 0; ni < 4; ++ni)
                    acc[mi][ni] = __builtin_amdgcn_mfma_f32_16x16x32_bf16(
                        af[mi], bf[ni], acc[mi][ni], 0, 0, 0);
            __builtin_amdgcn_s_setprio(0);
        }

        // ---- chunk boundary: ensure next buffer fully staged on all waves
        asm volatile("s_waitcnt vmcnt(0)" ::: "memory");
        __builtin_amdgcn_s_barrier();
    }

    // ---- epilogue: C/D layout col=lane&15, row=(lane>>4)*4+reg
#pragma unroll
    for (int mi = 0; mi < 8; ++mi) {
#pragma unroll
        for (int ni = 0; ni < 4; ++ni) {
            int orow = o0 + mi * 16 + lg * 4;
            int tcol = t0 + wid * 64 + ni * 16 + lr;
#pragma unroll
            for (int r = 0; r < 4; ++r) {
                out[((size_t)b * O_ + orow + r) * T_ + tcol] =
                    acc[mi][ni][r] + bias[orow + r];
            }
        }
    }
}

extern "C" void kernel_launch(void* const* d_in, const int* in_sizes, int n_in,
                              void* d_out, int out_size, void* d_ws, size_t ws_size,
                              hipStream_t stream) {
    const float* x    = (const float*)d_in[0];
    const float* w    = (const float*)d_in[1];
    const float* bias = (const float*)d_in[2];
    float* out        = (float*)d_out;

    unsigned short* wb  = (unsigned short*)d_ws;            // 2.62 MB
    unsigned short* xtp = wb + (size_t)KT * O_ * C_;        // 16*4128*512 bf16 = 67.7 MB

    padzero_kernel<<<(B_ * 32 * C_ + 255) / 256, 256, 0, stream>>>(xtp);
    wrepack_kernel<<<(KT * O_ * C_ + 255) / 256, 256, 0, stream>>>(w, wb);
    xtrans_kernel<<<dim3(T_ / 64, C_ / 64, B_), 256, 0, stream>>>(x, xtp);
    conv_gemm_kernel<<<512, 512, 0, stream>>>(wb, xtp, bias, out);
}